// Round 10
// baseline (629.747 us; speedup 1.0000x reference)
//
#include <hip/hip_runtime.h>
#include <hip/hip_bf16.h>
#include <hip/hip_fp16.h>

#define RN 4096
#define EN 131072
#define TN 1536
#define T2 768            // sample-pairs per row
#define SP 1040           // padded row stride in pairs
#define PADP 257          // front wrap-replica pairs
#define PN 256
#define NBOUNCE 12
#define NCHUNK 4          // chunk c -> XCDs {c, c+4} (R4/R7 validated)
#define CP 192            // pairs per chunk = 64 lanes x 3 pairs
#define NBKT 32           // edge-order buckets: (col>>11)*16 | (delay>>5)
// np.float32(np.log(1e-3))
#define LOG_GAMMA -6.90775528f
#define INV_SR (1.0f / 16000.0f)

#define rfl(x) __builtin_amdgcn_readfirstlane(x)

// ---------------- CSR build (edges bucket-ordered within each row) ----------
// Ordering key = (col-half, delay-bucket): all blocks sweep source halves and
// delay offsets in the same order -> instantaneous per-XCD L2 window ~2 MB.

__global__ void hist_kernel(const int* __restrict__ row, const int* __restrict__ col,
                            const int* __restrict__ delay,
                            int* __restrict__ cntB, int* __restrict__ cnt) {
    int e = blockIdx.x * blockDim.x + threadIdx.x;
    if (e >= EN) return;
    int r = row[e];
    int key = ((col[e] >> 11) << 4) | (delay[e] >> 5);
    atomicAdd(&cntB[r * NBKT + key], 1);
    atomicAdd(&cnt[r], 1);
}

// single block, 1024 threads: exclusive scan of even-rounded row totals.
__global__ void scan_kernel(const int* __restrict__ cnt, int* __restrict__ off) {
    __shared__ int part[1024];
    int tid = threadIdx.x;
    int v0 = cnt[tid * 4 + 0], v1 = cnt[tid * 4 + 1];
    int v2 = cnt[tid * 4 + 2], v3 = cnt[tid * 4 + 3];
    int p0 = (v0 + 1) & ~1, p1 = (v1 + 1) & ~1, p2 = (v2 + 1) & ~1, p3 = (v3 + 1) & ~1;
    part[tid] = p0 + p1 + p2 + p3;
    __syncthreads();
    for (int ofs = 1; ofs < 1024; ofs <<= 1) {
        int x = (tid >= ofs) ? part[tid - ofs] : 0;
        __syncthreads();
        part[tid] += x;
        __syncthreads();
    }
    int excl = (tid == 0) ? 0 : part[tid - 1];
    int o0 = excl, o1 = o0 + p0, o2 = o1 + p1, o3 = o2 + p2;
    off[tid * 4 + 0] = o0;
    off[tid * 4 + 1] = o1;
    off[tid * 4 + 2] = o2;
    off[tid * 4 + 3] = o3;
    if (tid == 1023) off[RN] = o3 + p3;
}

// one thread per row: serial exclusive prefix over the row's 32 bucket counts
__global__ void rowscan_kernel(const int* __restrict__ off, const int* __restrict__ cntB,
                               int* __restrict__ curB) {
    int r = blockIdx.x * 256 + threadIdx.x;
    if (r >= RN) return;
    int acc = off[r];
#pragma unroll
    for (int b = 0; b < NBKT; ++b) {
        curB[r * NBKT + b] = acc;
        acc += cntB[r * NBKT + b];
    }
}

// per edge: kernel value + precomputed relative byte offset into the padded layout.
// md.x = ((col*SP + PADP - dpair) << 2) | (delay & 1),  md.y = bits(kern)
__global__ void scatter_kernel(const int* __restrict__ row, const int* __restrict__ col,
                               const int* __restrict__ rid, const int* __restrict__ delay,
                               const float* __restrict__ basis,
                               const float* __restrict__ absorption,
                               const float* __restrict__ scattering,
                               int* __restrict__ curB, int2* __restrict__ mdarr) {
    int e = blockIdx.x * blockDim.x + threadIdx.x;
    if (e >= EN) return;
    int p = rid[e];
    float a = absorption[p];
    float s = scattering[p];
    float k = (1.0f - a) * (s * basis[e] + (1.0f - s) * basis[EN + e]);
    int d = delay[e];
    int c = col[e];
    int dpair = (d + 1) >> 1;                       // d in [0,512)
    int o = ((c * SP + PADP - dpair) << 2) | (d & 1);
    int key = ((c >> 11) << 4) | (d >> 5);
    int pos = atomicAdd(&curB[row[e] * NBKT + key], 1);
    mdarr[pos] = make_int2(o, __float_as_int(k));
}

// fill per-row pad slots (k=0, safe offset) + global tail pads
__global__ void padfill_kernel(const int* __restrict__ off, const int* __restrict__ cnt,
                               int2* __restrict__ mdarr) {
    int r = blockIdx.x * 256 + threadIdx.x;
    if (r < RN) {
        int n = cnt[r];
        if (n & 1) mdarr[off[r] + n] = make_int2(PADP << 2, 0);
    }
    if (r < 8) mdarr[off[RN] + r] = make_int2(PADP << 2, 0);
}

// ---------------- init: padded cur = half(x * window) ----------------

__global__ __launch_bounds__(256) void init_kernel(const float* __restrict__ x,
                                                   __half* __restrict__ cur) {
    int r = blockIdx.x;
    int tid = threadIdx.x;
    const float* xr = x + r * TN;
    uint* curp = (uint*)cur + (size_t)r * SP;
#pragma unroll
    for (int kk = 0; kk < 3; ++kk) {
        int q = tid + kk * 256;                     // pair index
        int t = q * 2;
        float wa = __expf(LOG_GAMMA * (float)t * INV_SR);
        float wb = __expf(LOG_GAMMA * (float)(t + 1) * INV_SR);
        __half2 h = __float22half2_rn(make_float2(xr[t] * wa, xr[t + 1] * wb));
        uint u = *(uint*)&h;
        curp[PADP + q] = u;
        if (q >= 511) curp[q - 511] = u;            // wrap replica
    }
}

// ---------------- bounce (EXACT R7/R9 structure — validated end-to-end) -------
// Block = 2 waves; wave w handles row rg*2+w, chunk of 192 pairs, 3 contiguous
// pairs per lane. bid = rg*4 + chunk -> chunk c lands only on XCDs {c, c+4}.
// Per edge per lane: ONE global_load_dwordx4 covers 3 pairs + realign dword.
// 2-edge software pipeline (A/B register sets), branchless even-padded CSR.

#define ISSUE(W, mo)                                                   \
    {                                                                  \
        const uint* rp_ = (const uint*)(curb + (size_t)((mo) & ~1u));  \
        W = *(const uint4*)(rp_ + pb);                                 \
    }

#define CONSUME(W, mo, kb)                                             \
    {                                                                  \
        float k_ = __uint_as_float((uint)(kb));                        \
        uint v0_, v1_, v2_;                                            \
        if ((mo) & 1u) {                                               \
            v0_ = __builtin_amdgcn_alignbit(W.y, W.x, 16);             \
            v1_ = __builtin_amdgcn_alignbit(W.z, W.y, 16);             \
            v2_ = __builtin_amdgcn_alignbit(W.w, W.z, 16);             \
        } else { v0_ = W.x; v1_ = W.y; v2_ = W.z; }                    \
        __half2 h0_ = *(__half2*)&v0_;                                 \
        __half2 h1_ = *(__half2*)&v1_;                                 \
        __half2 h2_ = *(__half2*)&v2_;                                 \
        a0 = fmaf(k_, __half2float(h0_.x), a0);                        \
        a1 = fmaf(k_, __half2float(h0_.y), a1);                        \
        a2 = fmaf(k_, __half2float(h1_.x), a2);                        \
        a3 = fmaf(k_, __half2float(h1_.y), a3);                        \
        a4 = fmaf(k_, __half2float(h2_.x), a4);                        \
        a5 = fmaf(k_, __half2float(h2_.y), a5);                        \
    }

__global__ __launch_bounds__(128, 8) void bounce_kernel(
        const __half* __restrict__ cur, __half* __restrict__ nxt,
        const int* __restrict__ offp, const int* __restrict__ ntot,
        const int2* __restrict__ mdarr) {
    int bid = blockIdx.x;
    int rg = bid >> 2;
    int chunk = bid & 3;
    int wave = threadIdx.x >> 6;
    int lane = threadIdx.x & 63;
    int r = rg * 2 + wave;
    int c0 = chunk * CP;
    int pb = c0 + lane * 3;                         // base pair of this lane's 3
    int e0 = rfl(offp[r]);
    int n  = rfl(ntot[r]);
    float a0 = 0.f, a1 = 0.f, a2 = 0.f, a3 = 0.f, a4 = 0.f, a5 = 0.f;
    const char* curb = (const char*)cur;

    if (n > 0) {
        int e1p = e0 + ((n + 1) & ~1);
        uint4 md01 = *(const uint4*)(mdarr + e0);   // e0 even -> 16B aligned
        uint moA = (uint)rfl((int)md01.x), kbA = (uint)rfl((int)md01.y);
        uint moB = (uint)rfl((int)md01.z), kbB = (uint)rfl((int)md01.w);
        uint4 WA, WB;
        ISSUE(WA, moA);
        ISSUE(WB, moB);
        for (int j = e0 + 2; j < e1p; j += 2) {
            uint4 mdn = *(const uint4*)(mdarr + j);
            uint moC = (uint)rfl((int)mdn.x), kbC = (uint)rfl((int)mdn.y);
            uint moD = (uint)rfl((int)mdn.z), kbD = (uint)rfl((int)mdn.w);
            CONSUME(WA, moA, kbA); ISSUE(WA, moC);
            CONSUME(WB, moB, kbB); ISSUE(WB, moD);
            moA = moC; kbA = kbC; moB = moD; kbB = kbD;
        }
        CONSUME(WA, moA, kbA);
        CONSUME(WB, moB, kbB);
    }

    __half2 h0 = __float22half2_rn(make_float2(a0, a1));
    __half2 h1 = __float22half2_rn(make_float2(a2, a3));
    __half2 h2 = __float22half2_rn(make_float2(a4, a5));
    uint u0 = *(uint*)&h0, u1 = *(uint*)&h1, u2 = *(uint*)&h2;
    uint* nxtp = (uint*)nxt + (size_t)r * SP;
    nxtp[PADP + pb]     = u0;
    nxtp[PADP + pb + 1] = u1;
    nxtp[PADP + pb + 2] = u2;
    if (pb + 2 >= 511) {                            // wrap replica writes
        if (pb     >= 511) nxtp[pb - 511] = u0;
        if (pb + 1 >= 511) nxtp[pb - 510] = u1;
        nxtp[pb - 509] = u2;
    }
}

// ---------------- detection (accumulated per bounce, fp32) ----------------

__global__ __launch_bounds__(128) void detect_kernel(
        const __half* __restrict__ buf, const float* __restrict__ w,
        const int* __restrict__ dd, float* __restrict__ det) {
    int cx = blockIdx.x;
    int r0 = blockIdx.y * 16;
    int tid = threadIdx.x;
    int tb = cx * 384 + tid;
    float acc0 = 0.f, acc1 = 0.f, acc2 = 0.f;
#pragma unroll 4
    for (int rr = 0; rr < 16; ++rr) {
        int r = r0 + rr;
        int d = dd[r];
        float wr = w[r];
        const __half* bufr = buf + (size_t)r * (SP * 2);
        int s0 = tb - d;           if (s0 < 0) s0 += TN;
        int s1 = tb + 128 - d;     if (s1 < 0) s1 += TN;
        int s2 = tb + 256 - d;     if (s2 < 0) s2 += TN;
        acc0 = fmaf(wr, __half2float(bufr[(PADP + (s0 >> 1)) * 2 + (s0 & 1)]), acc0);
        acc1 = fmaf(wr, __half2float(bufr[(PADP + (s1 >> 1)) * 2 + (s1 & 1)]), acc1);
        acc2 = fmaf(wr, __half2float(bufr[(PADP + (s2 >> 1)) * 2 + (s2 & 1)]), acc2);
    }
    atomicAdd(&det[tb], acc0);
    atomicAdd(&det[tb + 128], acc1);
    atomicAdd(&det[tb + 256], acc2);
}

__global__ void final_kernel(const float* __restrict__ det, float* __restrict__ out) {
    int t = blockIdx.x * 256 + threadIdx.x;
    if (t < TN) out[t] = det[t] * __expf(-LOG_GAMMA * (float)t * INV_SR);
}

// ---------------- launch ----------------

extern "C" void kernel_launch(void* const* d_in, const int* in_sizes, int n_in,
                              void* d_out, int out_size, void* d_ws, size_t ws_size,
                              hipStream_t stream) {
    const float* init_rad   = (const float*)d_in[0];
    const float* basis      = (const float*)d_in[1];
    const float* absorption = (const float*)d_in[2];
    const float* scattering = (const float*)d_in[3];
    const float* det_w      = (const float*)d_in[4];
    const int*   row        = (const int*)d_in[5];
    const int*   col        = (const int*)d_in[6];
    const int*   rid        = (const int*)d_in[7];
    const int*   delay      = (const int*)d_in[8];
    const int*   det_delay  = (const int*)d_in[9];
    float* out = (float*)d_out;

    char* ws = (char*)d_ws;
    size_t o = 0;
    auto alloc = [&](size_t bytes) {
        void* p = ws + o;
        o = (o + bytes + 255) & ~(size_t)255;
        return p;
    };
    int*    cntB   = (int*)alloc((size_t)RN * NBKT * 4);
    int*    curB   = (int*)alloc((size_t)RN * NBKT * 4);
    int*    cnt    = (int*)alloc(RN * 4);
    int*    off    = (int*)alloc((RN + 1) * 4);
    int2*   mdarr  = (int2*)alloc((size_t)(EN + RN + 8) * 8);
    __half* bufA   = (__half*)alloc((size_t)RN * SP * 4);
    __half* bufB   = (__half*)alloc((size_t)RN * SP * 4);
    float*  det    = (float*)alloc(TN * 4);

    hipMemsetAsync(cntB, 0, (size_t)RN * NBKT * 4, stream);
    hipMemsetAsync(cnt, 0, RN * 4, stream);
    hipMemsetAsync(det, 0, TN * 4, stream);

    hist_kernel<<<EN / 256, 256, 0, stream>>>(row, col, delay, cntB, cnt);
    scan_kernel<<<1, 1024, 0, stream>>>(cnt, off);
    rowscan_kernel<<<RN / 256, 256, 0, stream>>>(off, cntB, curB);
    scatter_kernel<<<EN / 256, 256, 0, stream>>>(row, col, rid, delay, basis,
                                                 absorption, scattering, curB, mdarr);
    padfill_kernel<<<RN / 256, 256, 0, stream>>>(off, cnt, mdarr);
    init_kernel<<<RN, 256, 0, stream>>>(init_rad, bufA);

    dim3 dgrid(NCHUNK, RN / 16);
    detect_kernel<<<dgrid, 128, 0, stream>>>(bufA, det_w, det_delay, det);

    __half* cur = bufA;
    __half* nxt = bufB;
    for (int b = 0; b < NBOUNCE; ++b) {
        bounce_kernel<<<(RN / 2) * NCHUNK, 128, 0, stream>>>(cur, nxt, off, cnt, mdarr);
        detect_kernel<<<dgrid, 128, 0, stream>>>(nxt, det_w, det_delay, det);
        __half* tmp = cur; cur = nxt; nxt = tmp;
    }

    final_kernel<<<TN / 256, 256, 0, stream>>>(det, out);
}